// Round 1
// baseline (48.709 us; speedup 1.0000x reference)
//
#include <hip/hip_runtime.h>

// Integrate-and-fire scan: x (T*B, C, H, W) f32, T=8.
// Viewed as (T, N) with N = B*C*H*W. Each thread owns 4 consecutive neurons
// (one float4) and runs the 8-step scan in registers.
// Memory-bound: 128 MiB in + 128 MiB out -> ~43 us floor at 6.3 TB/s.

#define T_STEPS 8

__global__ __launch_bounds__(256) void if_scan_kernel(
    const float4* __restrict__ x,
    const float* __restrict__ thr_p,
    float4* __restrict__ out,
    int n4)   // N/4 float4 elements per timestep
{
    const float th = thr_p[0];
    const int stride = gridDim.x * blockDim.x;

    for (int i = blockIdx.x * blockDim.x + threadIdx.x; i < n4; i += stride) {
        // Issue all 8 independent loads first for max memory-level parallelism.
        float4 xs[T_STEPS];
        #pragma unroll
        for (int t = 0; t < T_STEPS; ++t) {
            xs[t] = x[(size_t)t * n4 + i];
        }

        float mx = 0.f, my = 0.f, mz = 0.f, mw = 0.f;
        #pragma unroll
        for (int t = 0; t < T_STEPS; ++t) {
            float4 s;
            // integrate
            mx += xs[t].x; my += xs[t].y; mz += xs[t].z; mw += xs[t].w;
            // fire (same op order as reference: mem - th > 0)
            s.x = (mx - th > 0.f) ? 1.f : 0.f;
            s.y = (my - th > 0.f) ? 1.f : 0.f;
            s.z = (mz - th > 0.f) ? 1.f : 0.f;
            s.w = (mw - th > 0.f) ? 1.f : 0.f;
            // hard reset where spiked (mem * (1 - s) == select)
            mx = (s.x != 0.f) ? 0.f : mx;
            my = (s.y != 0.f) ? 0.f : my;
            mz = (s.z != 0.f) ? 0.f : mz;
            mw = (s.w != 0.f) ? 0.f : mw;

            out[(size_t)t * n4 + i] = s;
        }
    }
}

extern "C" void kernel_launch(void* const* d_in, const int* in_sizes, int n_in,
                              void* d_out, int out_size, void* d_ws, size_t ws_size,
                              hipStream_t stream) {
    const float* x   = (const float*)d_in[0];
    const float* thr = (const float*)d_in[1];
    float* out       = (float*)d_out;

    const int total = in_sizes[0];       // T*B*C*H*W = 33,554,432
    const int N     = total / T_STEPS;   // per-timestep elements = 4,194,304
    const int n4    = N / 4;             // float4 count = 1,048,576

    const int threads = 256;
    int blocks = (n4 + threads - 1) / threads;
    if (blocks > 2048) blocks = 2048;

    if_scan_kernel<<<blocks, threads, 0, stream>>>(
        (const float4*)x, thr, (float4*)out, n4);
}

// Round 3
// 47.283 us; speedup vs baseline: 1.0302x; 1.0302x over previous
//
#include <hip/hip_runtime.h>

// Integrate-and-fire scan: x (T*B, C, H, W) f32, T=8, viewed as (T, N).
// Each thread owns one float4 of neurons per grid-stride iter; 8-step scan
// in registers.
//
// Traffic insight (R1 rocprof): input (128 MiB) fits in the 256 MiB L3 and
// survives across graph replays, but cached output writes (132 MiB) evict
// half of it (FETCH_SIZE showed 64 MiB/replay). Nontemporal stores keep the
// output out of L2/L3 -> input stays L3-resident -> HBM traffic ~= writes.
//
// Note: __builtin_nontemporal_store requires a native vector type, not
// HIP's float4 struct -> use clang ext_vector_type(4).

#define T_STEPS 8

typedef float f32x4 __attribute__((ext_vector_type(4)));

__global__ __launch_bounds__(256) void if_scan_kernel(
    const f32x4* __restrict__ x,
    const float* __restrict__ thr_p,
    f32x4* __restrict__ out,
    int n4)   // N/4 vec4 elements per timestep
{
    const float th = thr_p[0];
    const int stride = gridDim.x * blockDim.x;

    for (int i = blockIdx.x * blockDim.x + threadIdx.x; i < n4; i += stride) {
        // 8 independent loads issued up front for MLP (cacheable: we WANT
        // the input resident in L3 across replays).
        f32x4 xs[T_STEPS];
        #pragma unroll
        for (int t = 0; t < T_STEPS; ++t) {
            xs[t] = x[(size_t)t * n4 + i];
        }

        f32x4 mem = {0.f, 0.f, 0.f, 0.f};
        #pragma unroll
        for (int t = 0; t < T_STEPS; ++t) {
            f32x4 s;
            mem += xs[t];                               // integrate
            #pragma unroll
            for (int j = 0; j < 4; ++j) {
                s[j]   = (mem[j] - th > 0.f) ? 1.f : 0.f;   // fire
                mem[j] = (s[j] != 0.f) ? 0.f : mem[j];      // hard reset
            }
            // Nontemporal: don't allocate output lines in L2/L3.
            __builtin_nontemporal_store(s, &out[(size_t)t * n4 + i]);
        }
    }
}

extern "C" void kernel_launch(void* const* d_in, const int* in_sizes, int n_in,
                              void* d_out, int out_size, void* d_ws, size_t ws_size,
                              hipStream_t stream) {
    const float* x   = (const float*)d_in[0];
    const float* thr = (const float*)d_in[1];
    float* out       = (float*)d_out;

    const int total = in_sizes[0];       // T*B*C*H*W = 33,554,432
    const int N     = total / T_STEPS;   // per-timestep elements = 4,194,304
    const int n4    = N / 4;             // vec4 count = 1,048,576

    const int threads = 256;
    int blocks = (n4 + threads - 1) / threads;
    if (blocks > 2048) blocks = 2048;

    if_scan_kernel<<<blocks, threads, 0, stream>>>(
        (const f32x4*)x, thr, (f32x4*)out, n4);
}

// Round 4
// 46.693 us; speedup vs baseline: 1.0432x; 1.0126x over previous
//
#include <hip/hip_runtime.h>

// Integrate-and-fire scan: x (T*B, C, H, W) f32, T=8, viewed as (T, N).
// One thread per float4 column, fully unrolled 8-step scan in registers.
//
// R3 counters: FETCH=64 MiB (half input L3-resident), WRITE=128 MiB, HBM at
// only 66% of achievable with VALUBusy 3% -> latency-bound, not BW-bound.
// This version drops the grid-stride loop (it serialized the 2nd column's
// loads behind the 1st column's dependent scan): exact-fit grid of 4096
// blocks, 1 column/thread, 8 loads issued at wave start, 2x wave-slot
// oversubscription for continuous backfill.

#define T_STEPS 8

typedef float f32x4 __attribute__((ext_vector_type(4)));

__global__ __launch_bounds__(256) void if_scan_kernel(
    const f32x4* __restrict__ x,
    const float* __restrict__ thr_p,
    f32x4* __restrict__ out,
    int n4)   // N/4 vec4 elements per timestep
{
    const int i = blockIdx.x * blockDim.x + threadIdx.x;
    if (i >= n4) return;
    const float th = thr_p[0];

    // 8 independent loads issued up front (cacheable: input should stay
    // L3-resident across graph replays).
    f32x4 xs[T_STEPS];
    #pragma unroll
    for (int t = 0; t < T_STEPS; ++t) {
        xs[t] = x[(size_t)t * n4 + i];
    }

    f32x4 mem = {0.f, 0.f, 0.f, 0.f};
    #pragma unroll
    for (int t = 0; t < T_STEPS; ++t) {
        f32x4 s;
        mem += xs[t];                                   // integrate
        #pragma unroll
        for (int j = 0; j < 4; ++j) {
            s[j]   = (mem[j] - th > 0.f) ? 1.f : 0.f;   // fire
            mem[j] = (s[j] != 0.f) ? 0.f : mem[j];      // hard reset
        }
        // Nontemporal: keeps ~4MB of dirty-eviction noise off HBM; free.
        __builtin_nontemporal_store(s, &out[(size_t)t * n4 + i]);
    }
}

extern "C" void kernel_launch(void* const* d_in, const int* in_sizes, int n_in,
                              void* d_out, int out_size, void* d_ws, size_t ws_size,
                              hipStream_t stream) {
    const float* x   = (const float*)d_in[0];
    const float* thr = (const float*)d_in[1];
    float* out       = (float*)d_out;

    const int total = in_sizes[0];       // T*B*C*H*W = 33,554,432
    const int N     = total / T_STEPS;   // per-timestep elements = 4,194,304
    const int n4    = N / 4;             // vec4 count = 1,048,576

    const int threads = 256;
    const int blocks  = (n4 + threads - 1) / threads;   // 4096: exact fit

    if_scan_kernel<<<blocks, threads, 0, stream>>>(
        (const f32x4*)x, thr, (f32x4*)out, n4);
}